// Round 17
// baseline (160.176 us; speedup 1.0000x reference)
//
#include <hip/hip_runtime.h>
#include <hip/hip_bf16.h>

#define BB 4
#define LL 4096
#define CC 512
#define DKK 64
#define OUTC 512
#define MTOT (BB*LL)         // 16384
#define NTOT (DKK+DKK+OUTC)  // 640

typedef __attribute__((ext_vector_type(8))) short short8;
typedef __attribute__((ext_vector_type(4))) float f32x4;
typedef __attribute__((ext_vector_type(16))) float f32x16;

// q is pre-scaled by 1/sqrt(dk) * log2(e) so attention uses exp2 directly.
#define QSCALE 0.18033688011112042f
#define MSHIFT 12.0f

#if __has_builtin(__builtin_amdgcn_exp2f)
#define EXP2(x) __builtin_amdgcn_exp2f(x)
#else
#define EXP2(x) exp2f(x)
#endif

__device__ __forceinline__ unsigned short f2bf(float f) {
    __hip_bfloat16 h = __float2bfloat16(f);
    return *reinterpret_cast<unsigned short*>(&h);
}

__device__ __forceinline__ float pswap_sum(float x) {
    unsigned u = __float_as_uint(x);
    auto r = __builtin_amdgcn_permlane32_swap(u, u, false, false);
    return __uint_as_float(r[0]) + __uint_as_float(r[1]);
}

// Tiled fragment layouts (all bf16):
//  qtb/ktb [b][T<128][c<4][lane<64][j<8]:
//     element = M[b][T*32 + (lane&31)][c*16 + (lane>>5)*8 + j]
//  vtt [b][T<128][og<8][f<4][lane<64][j<8]:
//     element = V[b][token = T*32 + (f&1)*16 + (lane>>5)*8 + j][o = og*64 + (f>>1)*32 + (lane&31)]

// ---------------- Kernel 0: convert x and W to bf16 ----------------
__global__ __launch_bounds__(256) void cvt_inputs(
    const float* __restrict__ x, const float* __restrict__ Wq,
    const float* __restrict__ Wk, const float* __restrict__ Wv,
    unsigned short* __restrict__ xb, unsigned short* __restrict__ wb)
{
    const int NX4 = (MTOT * CC) / 4;
    const int NW4 = (NTOT * CC) / 4;
    const int i = blockIdx.x * 256 + threadIdx.x;
    if (i >= NX4 + NW4) return;
    float4 t;
    ushort4 p;
    if (i < NX4) {
        t = ((const float4*)x)[i];
        p.x = f2bf(t.x); p.y = f2bf(t.y); p.z = f2bf(t.z); p.w = f2bf(t.w);
        ((ushort4*)xb)[i] = p;
    } else {
        const int wi = i - NX4;
        const int e = wi * 4;
        const float* src = (e < 64 * CC) ? (Wq + e)
                         : (e < 128 * CC) ? (Wk + (e - 64 * CC))
                         : (Wv + (e - 128 * CC));
        t = *(const float4*)src;
        p.x = f2bf(t.x); p.y = f2bf(t.y); p.z = f2bf(t.z); p.w = f2bf(t.w);
        ((ushort4*)wb)[wi] = p;
    }
}

// ---------------- Kernel 1: projection GEMM (bf16 MFMA) ----------------
__global__ __launch_bounds__(256, 2) void proj_gemm(
    const unsigned short* __restrict__ xb, const unsigned short* __restrict__ wb,
    const float* __restrict__ bq, const float* __restrict__ bk,
    const float* __restrict__ bv,
    unsigned short* __restrict__ qo, unsigned short* __restrict__ ko,
    unsigned short* __restrict__ vt)
{
    __shared__ unsigned short As[128 * 64];
    __shared__ unsigned short Bs[128 * 64];

    const int tid = threadIdx.x;
    const int wid = tid >> 6, lane = tid & 63;
    const int col = lane & 15, lg = lane >> 4;
    const int wm = wid >> 1, wn = wid & 1;
    const int m0 = blockIdx.x * 128, n0 = blockIdx.y * 128;

    f32x4 acc[4][4];
    #pragma unroll
    for (int i = 0; i < 4; ++i)
        #pragma unroll
        for (int j = 0; j < 4; ++j) acc[i][j] = (f32x4){0.f, 0.f, 0.f, 0.f};

    auto* As3 = (__attribute__((address_space(3))) unsigned short*)As;
    auto* Bs3 = (__attribute__((address_space(3))) unsigned short*)Bs;

    for (int kt = 0; kt < CC / 64; ++kt) {
        __syncthreads();
        #pragma unroll
        for (int i = 0; i < 4; ++i) {
            const int ch = wid * 4 + i;
            const int r = ch * 8 + (lane >> 3);
            const int c4 = lane & 7;
            const int sc4 = c4 ^ (r & 7);
            const unsigned short* ga = xb + (size_t)(m0 + r) * CC + kt * 64 + sc4 * 8;
            __builtin_amdgcn_global_load_lds(
                (const __attribute__((address_space(1))) void*)ga,
                (__attribute__((address_space(3))) void*)(As3 + ch * 512), 16, 0, 0);
            const unsigned short* gb = wb + (size_t)(n0 + r) * CC + kt * 64 + sc4 * 8;
            __builtin_amdgcn_global_load_lds(
                (const __attribute__((address_space(1))) void*)gb,
                (__attribute__((address_space(3))) void*)(Bs3 + ch * 512), 16, 0, 0);
        }
        __syncthreads();

        #pragma unroll
        for (int kk = 0; kk < 2; ++kk) {
            short8 af[4], bf[4];
            #pragma unroll
            for (int mf = 0; mf < 4; ++mf) {
                const int r = wm * 64 + mf * 16 + col;
                int off = r * 128 + kk * 64 + lg * 16;
                off ^= (r & 7) << 4;
                af[mf] = *(const short8*)((const char*)As + off);
            }
            #pragma unroll
            for (int nf = 0; nf < 4; ++nf) {
                const int r = wn * 64 + nf * 16 + col;
                int off = r * 128 + kk * 64 + lg * 16;
                off ^= (r & 7) << 4;
                bf[nf] = *(const short8*)((const char*)Bs + off);
            }
            #pragma unroll
            for (int mf = 0; mf < 4; ++mf)
                #pragma unroll
                for (int nf = 0; nf < 4; ++nf)
                    acc[mf][nf] = __builtin_amdgcn_mfma_f32_16x16x32_bf16(
                        af[mf], bf[nf], acc[mf][nf], 0, 0, 0);
        }
    }

    // epilogue -> fragment-tiled layouts
    const int nBase = n0 + wn * 64;
    #pragma unroll
    for (int nf = 0; nf < 4; ++nf) {
        const int n = nBase + nf * 16 + col;
        if (n < 128) {
            const bool isQ = (n < 64);
            const int nn = isQ ? n : (n - 64);
            const float bias = isQ ? bq[nn] : bk[nn];
            const float scl = isQ ? QSCALE : 1.0f;
            unsigned short* dst = isQ ? qo : ko;
            const int c = nn >> 4, h8 = (nn >> 3) & 1, jj = nn & 7;
            #pragma unroll
            for (int mf = 0; mf < 4; ++mf) {
                const int m = m0 + wm * 64 + mf * 16 + lg * 4;
                const int b_ = m >> 12;
                const int T = (m & 4095) >> 5;
                const size_t base =
                    ((((size_t)b_ * 128 + T) * 4 + c) * 64) * 8 + jj;
                #pragma unroll
                for (int r = 0; r < 4; ++r) {
                    const int l = (((m + r) & 31) + 32 * h8);
                    dst[base + (size_t)l * 8] = f2bf((acc[mf][nf][r] + bias) * scl);
                }
            }
        } else {
            const int o = n - 128;
            const float bias = bv[o];
            const int og = o >> 6;
            const int fo = (o >> 5) & 1;
            #pragma unroll
            for (int mf = 0; mf < 4; ++mf) {
                const int m = m0 + wm * 64 + mf * 16 + lg * 4;   // token of r=0
                const int b_ = m >> 12;
                const int tl = m & 4095;
                const int T = tl >> 5;
                const int kk = tl & 31;
                const int f = fo * 2 + ((kk >> 4) & 1);
                const int h8 = (kk >> 3) & 1;
                const int jb = kk & 7;                            // 0 or 4
                const int l = (o & 31) + 32 * h8;
                const size_t addr =
                    (((((size_t)b_ * 128 + T) * 8 + og) * 4 + f) * 64 + l) * 8 + jb;
                ushort4 p;
                p.x = f2bf(acc[mf][nf][0] + bias);
                p.y = f2bf(acc[mf][nf][1] + bias);
                p.z = f2bf(acc[mf][nf][2] + bias);
                p.w = f2bf(acc[mf][nf][3] + bias);
                *(ushort4*)&vt[addr] = p;
            }
        }
    }
}

// ---------------- Kernel 2: flash attention, LDS-shared K/V, counted vmcnt -
// 512 blocks x 256 thr (4 waves). Block = (b, q-group G<32, o-quarter oq<4);
// wave w owns q-tile 4*Geff+w, full k-range (no combine). K/V staged into
// 3-deep LDS buffers via global_load_lds; per step: wait OWN vmcnt(3)
// [stage t done, stage t+1 still in flight] -> raw s_barrier -> STAGE(t+2)
// -> compute(t). Loads stay in flight ACROSS barriers (T3/T4): no drain.
__global__ __launch_bounds__(256, 2) void attn_mfma(
    const unsigned short* __restrict__ qtb,
    const unsigned short* __restrict__ ktb,
    const unsigned short* __restrict__ vtt,
    float* __restrict__ out)
{
    __shared__ unsigned short Kst[3][2048];   // 12 KB (3 x 4KB)
    __shared__ unsigned short Vst[3][4096];   // 24 KB (3 x 8KB)

    const int tid  = threadIdx.x;
    const int wid  = tid >> 6;
    const int lane = tid & 63;
    const int m31  = lane & 31;
    const int hi   = lane >> 5;
    const int bid  = blockIdx.x;

    // decode: bid&7 = XCD (round-robin assumption, perf-only): batch pinned
    const int x  = bid & 7;
    const int b  = x >> 1;
    const int r_ = bid >> 3;               // 0..63
    const int oq = (x & 1) * 2 + (r_ & 1); // 0..3 (128 out-cols)
    const int G  = r_ >> 1;                // 0..31

    const unsigned short* Qb = qtb + (size_t)b * 128 * 2048;
    const unsigned short* Kb = ktb + (size_t)b * 128 * 2048;
    const unsigned short* Vb = vtt + (size_t)b * 128 * 16384;
    float* outb = out + (size_t)b * LL * OUTC;

    auto* Ks3 = (__attribute__((address_space(3))) unsigned short*)&Kst[0][0];
    auto* Vs3 = (__attribute__((address_space(3))) unsigned short*)&Vst[0][0];

    #pragma unroll 1
    for (int ph = 0; ph < 2; ++ph) {
        const int Geff = ph ? (31 - G) : G;
        const int Tmax = 4 * Geff + 3;
        const int Town = 4 * Geff + wid;
        const int q0   = Town * 32;

        // Q fragments for this wave's tile (coalesced 1KB loads)
        short8 qf[4];
        {
            const unsigned short* p = Qb + (size_t)Town * 2048 + lane * 8;
            #pragma unroll
            for (int c = 0; c < 4; ++c) qf[c] = *(const short8*)(p + c * 512);
        }

        f32x16 ac0, ac1, ac2, ac3;
        #pragma unroll
        for (int i = 0; i < 16; ++i) { ac0[i]=0.f; ac1[i]=0.f; ac2[i]=0.f; ac3[i]=0.f; }
        float ls = 0.f;

        auto STAGE = [&](int t, int bo) {
            // K chunk wid (1KB): lane-linear dest = what global_load_lds writes
            {
                const unsigned short* ks = Kb + (size_t)t * 2048 + wid * 512 + lane * 8;
                __builtin_amdgcn_global_load_lds(
                    (const __attribute__((address_space(1))) void*)ks,
                    (__attribute__((address_space(3))) void*)(Ks3 + bo * 2048 + wid * 512),
                    16, 0, 0);
            }
            // V chunks wid and wid+4
            #pragma unroll
            for (int e = 0; e < 2; ++e) {
                const int c = wid + e * 4;             // 0..7
                const unsigned short* vs = Vb + (size_t)t * 16384
                    + (size_t)(oq * 2 + (c >> 2)) * 2048 + (c & 3) * 512 + lane * 8;
                __builtin_amdgcn_global_load_lds(
                    (const __attribute__((address_space(1))) void*)vs,
                    (__attribute__((address_space(3))) void*)(Vs3 + bo * 4096 + c * 512),
                    16, 0, 0);
            }
        };

        STAGE(0, 0);
        STAGE(1, 1);

        int bo = 0;
        #pragma unroll 1
        for (int t = 0; t <= Tmax; ++t) {
            // wait for OWN stage-t loads (3); stage-(t+1)'s 3 stay in flight.
            if (t + 1 <= Tmax) {
                asm volatile("s_waitcnt vmcnt(3)" ::: "memory");
            } else {
                asm volatile("s_waitcnt vmcnt(0)" ::: "memory");
            }
            __builtin_amdgcn_s_barrier();        // all waves' stage-t visible
            __builtin_amdgcn_sched_barrier(0);
            if (t + 2 <= Tmax) {
                int bo2 = bo + 2; if (bo2 >= 3) bo2 -= 3;
                STAGE(t + 2, bo2);               // buf (t-1)%3: safe post-barrier
            }
            if (t <= Town) {
                short8 kf[4];
                #pragma unroll
                for (int c = 0; c < 4; ++c)
                    kf[c] = *(const short8*)&Kst[bo][c * 512 + lane * 8];

                f32x16 s;
                #pragma unroll
                for (int i = 0; i < 16; ++i) s[i] = 0.f;
                __builtin_amdgcn_s_setprio(1);
                #pragma unroll
                for (int c = 0; c < 4; ++c)
                    s = __builtin_amdgcn_mfma_f32_32x32x16_bf16(kf[c], qf[c], s, 0, 0, 0);
                __builtin_amdgcn_s_setprio(0);
                if (t == Town) {
                    #pragma unroll
                    for (int jj = 0; jj < 16; ++jj) {
                        const int pos = (jj & 3) + 8 * (jj >> 2) + 4 * hi;
                        if (pos > m31) s[jj] = -30000.f;
                    }
                }
                #pragma unroll
                for (int jj = 0; jj < 16; ++jj) s[jj] = EXP2(s[jj] - MSHIFT);
                {
                    float t0 = (s[0] + s[1]) + (s[2] + s[3]);
                    float t1 = (s[4] + s[5]) + (s[6] + s[7]);
                    float t2 = (s[8] + s[9]) + (s[10] + s[11]);
                    float t3 = (s[12] + s[13]) + (s[14] + s[15]);
                    ls += (t0 + t1) + (t2 + t3);
                }
                unsigned a0, a1, b0, b1, a2, a3, b2, b3;
                asm("v_cvt_pk_bf16_f32 %0, %1, %2" : "=v"(a0) : "v"(s[0]),  "v"(s[1]));
                asm("v_cvt_pk_bf16_f32 %0, %1, %2" : "=v"(a1) : "v"(s[2]),  "v"(s[3]));
                asm("v_cvt_pk_bf16_f32 %0, %1, %2" : "=v"(b0) : "v"(s[4]),  "v"(s[5]));
                asm("v_cvt_pk_bf16_f32 %0, %1, %2" : "=v"(b1) : "v"(s[6]),  "v"(s[7]));
                asm("v_cvt_pk_bf16_f32 %0, %1, %2" : "=v"(a2) : "v"(s[8]),  "v"(s[9]));
                asm("v_cvt_pk_bf16_f32 %0, %1, %2" : "=v"(a3) : "v"(s[10]), "v"(s[11]));
                asm("v_cvt_pk_bf16_f32 %0, %1, %2" : "=v"(b2) : "v"(s[12]), "v"(s[13]));
                asm("v_cvt_pk_bf16_f32 %0, %1, %2" : "=v"(b3) : "v"(s[14]), "v"(s[15]));
                auto r0 = __builtin_amdgcn_permlane32_swap(a0, b0, false, false);
                auto r1 = __builtin_amdgcn_permlane32_swap(a1, b1, false, false);
                auto r2 = __builtin_amdgcn_permlane32_swap(a2, b2, false, false);
                auto r3 = __builtin_amdgcn_permlane32_swap(a3, b3, false, false);
                union { unsigned u[4]; short8 s8; } pf0, pf1;
                pf0.u[0] = r0[0]; pf0.u[1] = r1[0]; pf0.u[2] = r0[1]; pf0.u[3] = r1[1];
                pf1.u[0] = r2[0]; pf1.u[1] = r3[0]; pf1.u[2] = r2[1]; pf1.u[3] = r3[1];

                short8 vf[8];
                #pragma unroll
                for (int c = 0; c < 8; ++c)
                    vf[c] = *(const short8*)&Vst[bo][c * 512 + lane * 8];

                __builtin_amdgcn_s_setprio(1);
                ac0 = __builtin_amdgcn_mfma_f32_32x32x16_bf16(vf[0], pf0.s8, ac0, 0, 0, 0);
                ac0 = __builtin_amdgcn_mfma_f32_32x32x16_bf16(vf[1], pf1.s8, ac0, 0, 0, 0);
                ac1 = __builtin_amdgcn_mfma_f32_32x32x16_bf16(vf[2], pf0.s8, ac1, 0, 0, 0);
                ac1 = __builtin_amdgcn_mfma_f32_32x32x16_bf16(vf[3], pf1.s8, ac1, 0, 0, 0);
                ac2 = __builtin_amdgcn_mfma_f32_32x32x16_bf16(vf[4], pf0.s8, ac2, 0, 0, 0);
                ac2 = __builtin_amdgcn_mfma_f32_32x32x16_bf16(vf[5], pf1.s8, ac2, 0, 0, 0);
                ac3 = __builtin_amdgcn_mfma_f32_32x32x16_bf16(vf[6], pf0.s8, ac3, 0, 0, 0);
                ac3 = __builtin_amdgcn_mfma_f32_32x32x16_bf16(vf[7], pf1.s8, ac3, 0, 0, 0);
                __builtin_amdgcn_s_setprio(0);
            }
            ++bo; if (bo == 3) bo = 0;
        }

        ls = pswap_sum(ls);
        const float inv = 1.f / ls;
        float* row = outb + (size_t)(q0 + m31) * OUTC + oq * 128 + hi * 4;
        #pragma unroll
        for (int g = 0; g < 4; ++g) {
            float4 w;
            w.x = ac0[g*4+0]*inv; w.y = ac0[g*4+1]*inv;
            w.z = ac0[g*4+2]*inv; w.w = ac0[g*4+3]*inv;
            *(float4*)(row + g * 8) = w;
            w.x = ac1[g*4+0]*inv; w.y = ac1[g*4+1]*inv;
            w.z = ac1[g*4+2]*inv; w.w = ac1[g*4+3]*inv;
            *(float4*)(row + 32 + g * 8) = w;
            w.x = ac2[g*4+0]*inv; w.y = ac2[g*4+1]*inv;
            w.z = ac2[g*4+2]*inv; w.w = ac2[g*4+3]*inv;
            *(float4*)(row + 64 + g * 8) = w;
            w.x = ac3[g*4+0]*inv; w.y = ac3[g*4+1]*inv;
            w.z = ac3[g*4+2]*inv; w.w = ac3[g*4+3]*inv;
            *(float4*)(row + 96 + g * 8) = w;
        }
        __builtin_amdgcn_s_barrier();   // LDS safe for next phase's STAGE(0)
        __builtin_amdgcn_sched_barrier(0);
    }
}

extern "C" void kernel_launch(void* const* d_in, const int* in_sizes, int n_in,
                              void* d_out, int out_size, void* d_ws, size_t ws_size,
                              hipStream_t stream) {
    const float* x  = (const float*)d_in[0];
    const float* Wq = (const float*)d_in[1];
    const float* bq = (const float*)d_in[2];
    const float* Wk = (const float*)d_in[3];
    const float* bk = (const float*)d_in[4];
    const float* Wv = (const float*)d_in[5];
    const float* bv = (const float*)d_in[6];
    float* out = (float*)d_out;

    unsigned short* xb  = (unsigned short*)d_ws;
    unsigned short* wb  = xb + (size_t)MTOT * CC;
    unsigned short* qbf = wb + (size_t)NTOT * CC;
    unsigned short* kbf = qbf + (size_t)MTOT * DKK;
    unsigned short* vtb = kbf + (size_t)MTOT * DKK;

    const int total4 = (MTOT * CC + NTOT * CC) / 4;
    cvt_inputs<<<(total4 + 255) / 256, 256, 0, stream>>>(x, Wq, Wk, Wv, xb, wb);

    dim3 gG(MTOT / 128, NTOT / 128);
    proj_gemm<<<gG, 256, 0, stream>>>(xb, wb, bq, bk, bv, qbf, kbf, vtb);

    attn_mfma<<<512, 256, 0, stream>>>(qbf, kbf, vtb, out);
}

// Round 18
// 126.500 us; speedup vs baseline: 1.2662x; 1.2662x over previous
//
#include <hip/hip_runtime.h>
#include <hip/hip_bf16.h>

#define BB 4
#define LL 4096
#define CC 512
#define DKK 64
#define OUTC 512
#define MTOT (BB*LL)         // 16384
#define NTOT (DKK+DKK+OUTC)  // 640

typedef __attribute__((ext_vector_type(8))) short short8;
typedef __attribute__((ext_vector_type(4))) float f32x4;
typedef __attribute__((ext_vector_type(16))) float f32x16;

// q is pre-scaled by 1/sqrt(dk) * log2(e) so attention uses exp2 directly.
#define QSCALE 0.18033688011112042f
#define MSHIFT 12.0f

#if __has_builtin(__builtin_amdgcn_exp2f)
#define EXP2(x) __builtin_amdgcn_exp2f(x)
#else
#define EXP2(x) exp2f(x)
#endif

__device__ __forceinline__ unsigned short f2bf(float f) {
    __hip_bfloat16 h = __float2bfloat16(f);
    return *reinterpret_cast<unsigned short*>(&h);
}

__device__ __forceinline__ float pswap_sum(float x) {
    unsigned u = __float_as_uint(x);
    auto r = __builtin_amdgcn_permlane32_swap(u, u, false, false);
    return __uint_as_float(r[0]) + __uint_as_float(r[1]);
}

// Tiled fragment layouts (all bf16):
//  qtb/ktb [b][T<128][c<4][lane<64][j<8]:
//     element = M[b][T*32 + (lane&31)][c*16 + (lane>>5)*8 + j]
//  vtt [b][T<128][og<8][f<4][lane<64][j<8]:
//     element = V[b][token = T*32 + (f&1)*16 + (lane>>5)*8 + j][o = og*64 + (f>>1)*32 + (lane&31)]

// ---------------- Kernel 0: convert x and W to bf16 ----------------
__global__ __launch_bounds__(256) void cvt_inputs(
    const float* __restrict__ x, const float* __restrict__ Wq,
    const float* __restrict__ Wk, const float* __restrict__ Wv,
    unsigned short* __restrict__ xb, unsigned short* __restrict__ wb)
{
    const int NX4 = (MTOT * CC) / 4;
    const int NW4 = (NTOT * CC) / 4;
    const int i = blockIdx.x * 256 + threadIdx.x;
    if (i >= NX4 + NW4) return;
    float4 t;
    ushort4 p;
    if (i < NX4) {
        t = ((const float4*)x)[i];
        p.x = f2bf(t.x); p.y = f2bf(t.y); p.z = f2bf(t.z); p.w = f2bf(t.w);
        ((ushort4*)xb)[i] = p;
    } else {
        const int wi = i - NX4;
        const int e = wi * 4;
        const float* src = (e < 64 * CC) ? (Wq + e)
                         : (e < 128 * CC) ? (Wk + (e - 64 * CC))
                         : (Wv + (e - 128 * CC));
        t = *(const float4*)src;
        p.x = f2bf(t.x); p.y = f2bf(t.y); p.z = f2bf(t.z); p.w = f2bf(t.w);
        ((ushort4*)wb)[wi] = p;
    }
}

// ---------------- Kernel 1: projection GEMM (bf16 MFMA) ----------------
__global__ __launch_bounds__(256, 2) void proj_gemm(
    const unsigned short* __restrict__ xb, const unsigned short* __restrict__ wb,
    const float* __restrict__ bq, const float* __restrict__ bk,
    const float* __restrict__ bv,
    unsigned short* __restrict__ qo, unsigned short* __restrict__ ko,
    unsigned short* __restrict__ vt)
{
    __shared__ unsigned short As[128 * 64];
    __shared__ unsigned short Bs[128 * 64];

    const int tid = threadIdx.x;
    const int wid = tid >> 6, lane = tid & 63;
    const int col = lane & 15, lg = lane >> 4;
    const int wm = wid >> 1, wn = wid & 1;
    const int m0 = blockIdx.x * 128, n0 = blockIdx.y * 128;

    f32x4 acc[4][4];
    #pragma unroll
    for (int i = 0; i < 4; ++i)
        #pragma unroll
        for (int j = 0; j < 4; ++j) acc[i][j] = (f32x4){0.f, 0.f, 0.f, 0.f};

    auto* As3 = (__attribute__((address_space(3))) unsigned short*)As;
    auto* Bs3 = (__attribute__((address_space(3))) unsigned short*)Bs;

    for (int kt = 0; kt < CC / 64; ++kt) {
        __syncthreads();
        #pragma unroll
        for (int i = 0; i < 4; ++i) {
            const int ch = wid * 4 + i;
            const int r = ch * 8 + (lane >> 3);
            const int c4 = lane & 7;
            const int sc4 = c4 ^ (r & 7);
            const unsigned short* ga = xb + (size_t)(m0 + r) * CC + kt * 64 + sc4 * 8;
            __builtin_amdgcn_global_load_lds(
                (const __attribute__((address_space(1))) void*)ga,
                (__attribute__((address_space(3))) void*)(As3 + ch * 512), 16, 0, 0);
            const unsigned short* gb = wb + (size_t)(n0 + r) * CC + kt * 64 + sc4 * 8;
            __builtin_amdgcn_global_load_lds(
                (const __attribute__((address_space(1))) void*)gb,
                (__attribute__((address_space(3))) void*)(Bs3 + ch * 512), 16, 0, 0);
        }
        __syncthreads();

        #pragma unroll
        for (int kk = 0; kk < 2; ++kk) {
            short8 af[4], bf[4];
            #pragma unroll
            for (int mf = 0; mf < 4; ++mf) {
                const int r = wm * 64 + mf * 16 + col;
                int off = r * 128 + kk * 64 + lg * 16;
                off ^= (r & 7) << 4;
                af[mf] = *(const short8*)((const char*)As + off);
            }
            #pragma unroll
            for (int nf = 0; nf < 4; ++nf) {
                const int r = wn * 64 + nf * 16 + col;
                int off = r * 128 + kk * 64 + lg * 16;
                off ^= (r & 7) << 4;
                bf[nf] = *(const short8*)((const char*)Bs + off);
            }
            #pragma unroll
            for (int mf = 0; mf < 4; ++mf)
                #pragma unroll
                for (int nf = 0; nf < 4; ++nf)
                    acc[mf][nf] = __builtin_amdgcn_mfma_f32_16x16x32_bf16(
                        af[mf], bf[nf], acc[mf][nf], 0, 0, 0);
        }
    }

    // epilogue -> fragment-tiled layouts
    const int nBase = n0 + wn * 64;
    #pragma unroll
    for (int nf = 0; nf < 4; ++nf) {
        const int n = nBase + nf * 16 + col;
        if (n < 128) {
            const bool isQ = (n < 64);
            const int nn = isQ ? n : (n - 64);
            const float bias = isQ ? bq[nn] : bk[nn];
            const float scl = isQ ? QSCALE : 1.0f;
            unsigned short* dst = isQ ? qo : ko;
            const int c = nn >> 4, h8 = (nn >> 3) & 1, jj = nn & 7;
            #pragma unroll
            for (int mf = 0; mf < 4; ++mf) {
                const int m = m0 + wm * 64 + mf * 16 + lg * 4;
                const int b_ = m >> 12;
                const int T = (m & 4095) >> 5;
                const size_t base =
                    ((((size_t)b_ * 128 + T) * 4 + c) * 64) * 8 + jj;
                #pragma unroll
                for (int r = 0; r < 4; ++r) {
                    const int l = (((m + r) & 31) + 32 * h8);
                    dst[base + (size_t)l * 8] = f2bf((acc[mf][nf][r] + bias) * scl);
                }
            }
        } else {
            const int o = n - 128;
            const float bias = bv[o];
            const int og = o >> 6;
            const int fo = (o >> 5) & 1;
            #pragma unroll
            for (int mf = 0; mf < 4; ++mf) {
                const int m = m0 + wm * 64 + mf * 16 + lg * 4;   // token of r=0
                const int b_ = m >> 12;
                const int tl = m & 4095;
                const int T = tl >> 5;
                const int kk = tl & 31;
                const int f = fo * 2 + ((kk >> 4) & 1);
                const int h8 = (kk >> 3) & 1;
                const int jb = kk & 7;                            // 0 or 4
                const int l = (o & 31) + 32 * h8;
                const size_t addr =
                    (((((size_t)b_ * 128 + T) * 8 + og) * 4 + f) * 64 + l) * 8 + jb;
                ushort4 p;
                p.x = f2bf(acc[mf][nf][0] + bias);
                p.y = f2bf(acc[mf][nf][1] + bias);
                p.z = f2bf(acc[mf][nf][2] + bias);
                p.w = f2bf(acc[mf][nf][3] + bias);
                *(ushort4*)&vt[addr] = p;
            }
        }
    }
}

// ---------------- Kernel 2: flash attention, 64-o waves, 4 waves/SIMD ------
// 1024 blocks x 256 thr = 4096 waves (4 blocks/CU -> 4 waves/SIMD). Wave =
// (b, jp, og<8, par<2): 32 q-rows x 64 out-cols, k-steps of its parity, for
// tile jp then 127-jp (65 steps each). Small wave state (acc 2xf32x16 = 32
// regs, total ~115) fits the 128-reg cap of launch_bounds(256,4) => real
// 4 waves/SIMD to cover the QK->SMAX->PV serial chain. Incremental K/V
// pointers kill per-step address VALU.
__global__ __launch_bounds__(256, 4) void attn_mfma(
    const unsigned short* __restrict__ qtb,
    const unsigned short* __restrict__ ktb,
    const unsigned short* __restrict__ vtt,
    float* __restrict__ out)
{
    __shared__ float xch[2][64][34];   // 17.4 KB: par1 -> par0 combine

    const int tid  = threadIdx.x;
    const int wid  = tid >> 6;
    const int lane = tid & 63;
    const int m31  = lane & 31;
    const int hi   = lane >> 5;
    const int bid  = blockIdx.x;

    // decode: bid = jp*16 + z; z&7 = XCD (round-robin assumption, perf-only)
    const int jp  = bid >> 4;                 // 0..63
    const int z   = bid & 15;
    const int x   = z & 7;
    const int b   = x >> 1;                   // batch pinned to XCD pair
    const int oh  = (z >> 3) * 2 + (x & 1);   // 0..3
    const int og  = oh * 2 + (wid >> 1);      // 0..7 (64 out-cols)
    const int par = wid & 1;                  // K parity
    const int slot = wid >> 1;

    const unsigned short* Qb = qtb + (size_t)b * 128 * 2048;
    const unsigned short* Kb = ktb + (size_t)b * 128 * 2048;
    const unsigned short* Vb = vtt + (size_t)b * 128 * 16384;
    float* outb = out + (size_t)b * LL * OUTC;

    #pragma unroll 1
    for (int ph = 0; ph < 2; ++ph) {
        const int T  = ph ? (127 - jp) : jp;
        const int q0 = T * 32;

        // Q fragments (coalesced 1KB loads)
        short8 qf[4];
        {
            const unsigned short* p = Qb + (size_t)T * 2048 + lane * 8;
            #pragma unroll
            for (int c = 0; c < 4; ++c) qf[c] = *(const short8*)(p + c * 512);
        }

        f32x16 ac0, ac1;
        #pragma unroll
        for (int i = 0; i < 16; ++i) { ac0[i] = 0.f; ac1[i] = 0.f; }
        float ls = 0.f;

        // incremental pointers (stride 2 tiles per iteration)
        const unsigned short* kp = Kb + (size_t)par * 2048 + lane * 8;
        const unsigned short* vp = Vb + (size_t)par * 16384 + og * 2048 + lane * 8;

        #pragma unroll 1
        for (int t = par; t <= T; t += 2) {
            short8 kf[4], vf[4];
            kf[0] = *(const short8*)(kp);
            kf[1] = *(const short8*)(kp + 512);
            kf[2] = *(const short8*)(kp + 1024);
            kf[3] = *(const short8*)(kp + 1536);
            vf[0] = *(const short8*)(vp);
            vf[1] = *(const short8*)(vp + 512);
            vf[2] = *(const short8*)(vp + 1024);
            vf[3] = *(const short8*)(vp + 1536);
            kp += 4096;      // 2 tiles * 2048
            vp += 32768;     // 2 tiles * 16384

            f32x16 s;
            #pragma unroll
            for (int i = 0; i < 16; ++i) s[i] = 0.f;
            __builtin_amdgcn_s_setprio(1);
            #pragma unroll
            for (int c = 0; c < 4; ++c)
                s = __builtin_amdgcn_mfma_f32_32x32x16_bf16(kf[c], qf[c], s, 0, 0, 0);
            __builtin_amdgcn_s_setprio(0);
            if (t == T) {
                #pragma unroll
                for (int jj = 0; jj < 16; ++jj) {
                    const int pos = (jj & 3) + 8 * (jj >> 2) + 4 * hi;
                    if (pos > m31) s[jj] = -30000.f;
                }
            }
            #pragma unroll
            for (int jj = 0; jj < 16; ++jj) s[jj] = EXP2(s[jj] - MSHIFT);
            {
                float t0 = (s[0] + s[1]) + (s[2] + s[3]);
                float t1 = (s[4] + s[5]) + (s[6] + s[7]);
                float t2 = (s[8] + s[9]) + (s[10] + s[11]);
                float t3 = (s[12] + s[13]) + (s[14] + s[15]);
                ls += (t0 + t1) + (t2 + t3);
            }
            unsigned a0, a1, b0, b1, a2, a3, b2, b3;
            asm("v_cvt_pk_bf16_f32 %0, %1, %2" : "=v"(a0) : "v"(s[0]),  "v"(s[1]));
            asm("v_cvt_pk_bf16_f32 %0, %1, %2" : "=v"(a1) : "v"(s[2]),  "v"(s[3]));
            asm("v_cvt_pk_bf16_f32 %0, %1, %2" : "=v"(b0) : "v"(s[4]),  "v"(s[5]));
            asm("v_cvt_pk_bf16_f32 %0, %1, %2" : "=v"(b1) : "v"(s[6]),  "v"(s[7]));
            asm("v_cvt_pk_bf16_f32 %0, %1, %2" : "=v"(a2) : "v"(s[8]),  "v"(s[9]));
            asm("v_cvt_pk_bf16_f32 %0, %1, %2" : "=v"(a3) : "v"(s[10]), "v"(s[11]));
            asm("v_cvt_pk_bf16_f32 %0, %1, %2" : "=v"(b2) : "v"(s[12]), "v"(s[13]));
            asm("v_cvt_pk_bf16_f32 %0, %1, %2" : "=v"(b3) : "v"(s[14]), "v"(s[15]));
            auto r0 = __builtin_amdgcn_permlane32_swap(a0, b0, false, false);
            auto r1 = __builtin_amdgcn_permlane32_swap(a1, b1, false, false);
            auto r2 = __builtin_amdgcn_permlane32_swap(a2, b2, false, false);
            auto r3 = __builtin_amdgcn_permlane32_swap(a3, b3, false, false);
            union { unsigned u[4]; short8 s8; } pf0, pf1;
            pf0.u[0] = r0[0]; pf0.u[1] = r1[0]; pf0.u[2] = r0[1]; pf0.u[3] = r1[1];
            pf1.u[0] = r2[0]; pf1.u[1] = r3[0]; pf1.u[2] = r2[1]; pf1.u[3] = r3[1];

            __builtin_amdgcn_s_setprio(1);
            ac0 = __builtin_amdgcn_mfma_f32_32x32x16_bf16(vf[0], pf0.s8, ac0, 0, 0, 0);
            ac0 = __builtin_amdgcn_mfma_f32_32x32x16_bf16(vf[1], pf1.s8, ac0, 0, 0, 0);
            ac1 = __builtin_amdgcn_mfma_f32_32x32x16_bf16(vf[2], pf0.s8, ac1, 0, 0, 0);
            ac1 = __builtin_amdgcn_mfma_f32_32x32x16_bf16(vf[3], pf1.s8, ac1, 0, 0, 0);
            __builtin_amdgcn_s_setprio(0);
        }
        ls = pswap_sum(ls);

        __syncthreads();
        if (par) {
            float* dst = &xch[slot][lane][0];
            #pragma unroll
            for (int i = 0; i < 16; ++i) { dst[i] = ac0[i]; dst[16 + i] = ac1[i]; }
            dst[32] = ls;
        }
        __syncthreads();
        if (!par) {
            const float* src = &xch[slot][lane][0];
            const float inv = 1.f / (ls + src[32]);
            float* row = outb + (size_t)(q0 + m31) * OUTC + og * 64 + hi * 4;
            #pragma unroll
            for (int g = 0; g < 4; ++g) {
                float4 w;
                w.x = (ac0[g*4+0] + src[g*4+0]) * inv;
                w.y = (ac0[g*4+1] + src[g*4+1]) * inv;
                w.z = (ac0[g*4+2] + src[g*4+2]) * inv;
                w.w = (ac0[g*4+3] + src[g*4+3]) * inv;
                *(float4*)(row + g * 8) = w;
                w.x = (ac1[g*4+0] + src[16+g*4+0]) * inv;
                w.y = (ac1[g*4+1] + src[16+g*4+1]) * inv;
                w.z = (ac1[g*4+2] + src[16+g*4+2]) * inv;
                w.w = (ac1[g*4+3] + src[16+g*4+3]) * inv;
                *(float4*)(row + 32 + g * 8) = w;
            }
        }
    }
}

extern "C" void kernel_launch(void* const* d_in, const int* in_sizes, int n_in,
                              void* d_out, int out_size, void* d_ws, size_t ws_size,
                              hipStream_t stream) {
    const float* x  = (const float*)d_in[0];
    const float* Wq = (const float*)d_in[1];
    const float* bq = (const float*)d_in[2];
    const float* Wk = (const float*)d_in[3];
    const float* bk = (const float*)d_in[4];
    const float* Wv = (const float*)d_in[5];
    const float* bv = (const float*)d_in[6];
    float* out = (float*)d_out;

    unsigned short* xb  = (unsigned short*)d_ws;
    unsigned short* wb  = xb + (size_t)MTOT * CC;
    unsigned short* qbf = wb + (size_t)NTOT * CC;
    unsigned short* kbf = qbf + (size_t)MTOT * DKK;
    unsigned short* vtb = kbf + (size_t)MTOT * DKK;

    const int total4 = (MTOT * CC + NTOT * CC) / 4;
    cvt_inputs<<<(total4 + 255) / 256, 256, 0, stream>>>(x, Wq, Wk, Wv, xb, wb);

    dim3 gG(MTOT / 128, NTOT / 128);
    proj_gemm<<<gG, 256, 0, stream>>>(xb, wb, bq, bk, bv, qbf, kbf, vtb);

    attn_mfma<<<1024, 256, 0, stream>>>(qbf, kbf, vtb, out);
}